// Round 3
// baseline (51.320 us; speedup 1.0000x reference)
//
#include <hip/hip_runtime.h>
#include <float.h>

#define BT 8
#define NV 10000
#define NB 16384
#define NS 4096
#define NPTS (BT * NS)                    // 32768 boundary points
#define PTS_PER_BLOCK 2048                // 256 threads * 8 points
#define SBLOCKS (NPTS / PTS_PER_BLOCK)    // 16
#define MAXCH 320                         // verts per LDS tile (10 KB duplicated)

typedef float v2f __attribute__((ext_vector_type(2)));

// Packed fp32 FMA: two independent FMAs per instruction (VOP3P, CDNA2+).
__device__ __forceinline__ v2f pk_fma(v2f a, v2f b, v2f c) {
    v2f d;
    asm("v_pk_fma_f32 %0, %1, %2, %3" : "=v"(d) : "v"(a), "v"(b), "v"(c));
    return d;
}
// 3-input min in one instruction.
__device__ __forceinline__ float min3f(float a, float b, float c) {
    float d;
    asm("v_min3_f32 %0, %1, %2, %3" : "=v"(d) : "v"(a), "v"(b), "v"(c));
    return d;
}

// Stage 1: partial min over a vertex chunk, 8 points/thread packed as 4 float2.
// grid.x = SBLOCKS * vchunks; block = 256
__global__ void __launch_bounds__(256, 4)
stage1(const float* __restrict__ verts, const float4* __restrict__ bds4,
       const int* __restrict__ idx, float* __restrict__ pmin, int ch) {
    __shared__ float4 sv[2 * MAXCH];     // per vertex: (x,x,y,y),(z,z,s,s), pre *-2
    const int sblk  = blockIdx.x % SBLOCKS;
    const int chunk = blockIdx.x / SBLOCKS;
    const int b  = sblk >> 1;            // 2 point-blocks per batch (2048*2=NS)
    const int p0 = sblk * PTS_PER_BLOCK;
    const int v0 = chunk * ch;
    const int vend = (v0 + ch < NV) ? (v0 + ch) : NV;

    v2f bx[4], by[4], bz[4], m[4];
#pragma unroll
    for (int pp = 0; pp < 4; ++pp) {
        int pt0 = p0 + threadIdx.x + (2 * pp) * 256;
        int pt1 = pt0 + 256;
        float4 q0 = bds4[(size_t)b * NB + idx[pt0 & (NS - 1)]];
        float4 q1 = bds4[(size_t)b * NB + idx[pt1 & (NS - 1)]];
        bx[pp] = (v2f){q0.x, q1.x};
        by[pp] = (v2f){q0.y, q1.y};
        bz[pp] = (v2f){q0.z, q1.z};
        m[pp]  = (v2f){FLT_MAX, FLT_MAX};
    }

    for (int t0 = v0; t0 < vend; t0 += MAXCH) {
        const int tn = (MAXCH < vend - t0) ? MAXCH : (vend - t0);
        __syncthreads();
        for (int i = threadIdx.x; i < tn; i += 256) {
            const float* vp = verts + (size_t)(b * NV + t0 + i) * 3;
            float x = vp[0], y = vp[1], z = vp[2];
            float s = x * x + y * y + z * z;
            float nx = -2.0f * x, ny = -2.0f * y, nz = -2.0f * z;
            sv[2 * i]     = make_float4(nx, nx, ny, ny);
            sv[2 * i + 1] = make_float4(nz, nz, s, s);
        }
        __syncthreads();

        int v = 0;
        for (; v + 2 <= tn; v += 2) {
            float4 a0 = sv[2 * v],     b0 = sv[2 * v + 1];
            float4 a1 = sv[2 * v + 2], b1 = sv[2 * v + 3];
            v2f qx0 = {a0.x, a0.y}, qy0 = {a0.z, a0.w};
            v2f qz0 = {b0.x, b0.y}, qw0 = {b0.z, b0.w};
            v2f qx1 = {a1.x, a1.y}, qy1 = {a1.z, a1.w};
            v2f qz1 = {b1.x, b1.y}, qw1 = {b1.z, b1.w};
#pragma unroll
            for (int pp = 0; pp < 4; ++pp) {
                v2f t0v = pk_fma(bx[pp], qx0, pk_fma(by[pp], qy0, pk_fma(bz[pp], qz0, qw0)));
                v2f t1v = pk_fma(bx[pp], qx1, pk_fma(by[pp], qy1, pk_fma(bz[pp], qz1, qw1)));
                m[pp].x = min3f(m[pp].x, t0v.x, t1v.x);
                m[pp].y = min3f(m[pp].y, t0v.y, t1v.y);
            }
        }
        if (v < tn) {  // odd tail vertex
            float4 a0 = sv[2 * v], b0 = sv[2 * v + 1];
            v2f qx0 = {a0.x, a0.y}, qy0 = {a0.z, a0.w};
            v2f qz0 = {b0.x, b0.y}, qw0 = {b0.z, b0.w};
#pragma unroll
            for (int pp = 0; pp < 4; ++pp) {
                v2f t0v = pk_fma(bx[pp], qx0, pk_fma(by[pp], qy0, pk_fma(bz[pp], qz0, qw0)));
                m[pp].x = fminf(m[pp].x, t0v.x);
                m[pp].y = fminf(m[pp].y, t0v.y);
            }
        }
    }

#pragma unroll
    for (int pp = 0; pp < 4; ++pp) {
        int pt0 = p0 + threadIdx.x + (2 * pp) * 256;
        pmin[(size_t)chunk * NPTS + pt0]       = m[pp].x;
        pmin[(size_t)chunk * NPTS + pt0 + 256] = m[pp].y;
    }
}

// Stage 2: combine chunk mins, add sq_b, apply mask, per-block sum.
__global__ void stage2(const float* __restrict__ pmin, const float4* __restrict__ bds4,
                       const int* __restrict__ idx, float* __restrict__ bsum,
                       int vchunks) {
    int pt = blockIdx.x * 256 + threadIdx.x;
    int b = pt >> 12;           // / NS
    int s = pt & (NS - 1);
    int j = idx[s];
    float4 bp = bds4[(size_t)b * NB + j];
    float md = FLT_MAX;
    for (int c = 0; c < vchunks; ++c)
        md = fminf(md, pmin[(size_t)c * NPTS + pt]);
    float sqb = bp.x * bp.x + bp.y * bp.y + bp.z * bp.z;
    float val = (md + sqb) * bp.w * (1.0f / (float)NPTS);

    for (int o = 32; o > 0; o >>= 1) val += __shfl_down(val, o, 64);
    __shared__ float red[4];
    if ((threadIdx.x & 63) == 0) red[threadIdx.x >> 6] = val;
    __syncthreads();
    if (threadIdx.x == 0) bsum[blockIdx.x] = red[0] + red[1] + red[2] + red[3];
}

// Stage 3: final sum of 128 block partials -> scalar
__global__ void stage3(const float* __restrict__ bsum, float* __restrict__ out) {
    float v = bsum[threadIdx.x];  // 128 threads
    for (int o = 32; o > 0; o >>= 1) v += __shfl_down(v, o, 64);
    __shared__ float r[2];
    if ((threadIdx.x & 63) == 0) r[threadIdx.x >> 6] = v;
    __syncthreads();
    if (threadIdx.x == 0) out[0] = r[0] + r[1];
}

extern "C" void kernel_launch(void* const* d_in, const int* in_sizes, int n_in,
                              void* d_out, int out_size, void* d_ws, size_t ws_size,
                              hipStream_t stream) {
    const float*  verts = (const float*)d_in[0];
    const float4* bds4  = (const float4*)d_in[1];  // (BT, NB, 4) rows
    const int*    idx   = (const int*)d_in[3];     // int32
    float* out = (float*)d_out;

    char* ws = (char*)d_ws;
    size_t per_chunk = (size_t)NPTS * sizeof(float);   // 128 KB of partial mins
    size_t rem = (ws_size > 4096) ? (ws_size - 4096) : 0;
    int vchunks = (int)(rem / per_chunk);
    if (vchunks > 64) vchunks = 64;   // grid = 16*64 = 1024 blocks = 4/CU
    if (vchunks < 1)  vchunks = 1;    // stage1 tiles internally, any count works
    float* pmin = (float*)ws;
    float* bsum = (float*)(ws + (size_t)vchunks * per_chunk);  // 128 floats

    int ch = (NV + vchunks - 1) / vchunks;

    stage1<<<SBLOCKS * vchunks, 256, 0, stream>>>(verts, bds4, idx, pmin, ch);
    stage2<<<NPTS / 256, 256, 0, stream>>>(pmin, bds4, idx, bsum, vchunks);
    stage3<<<1, 128, 0, stream>>>(bsum, out);
}

// Round 6
// 45.114 us; speedup vs baseline: 1.1376x; 1.1376x over previous
//
#include <hip/hip_runtime.h>
#include <float.h>

#define BT 8
#define NV 10000
#define NB 16384
#define NS 4096
#define NPTS (BT * NS)          // 32768 points
#define PTSB 2048               // points per block (256 thr * 8 pts)
#define PB (NPTS / PTSB)        // 16 point blocks
#define VCH 32                  // vertex chunks
#define CH 313                  // ceil(NV/VCH)
#define SVMAX 316               // CH padded to multiple of 4

__device__ __forceinline__ float min3f(float a, float b, float c) {
    float d;
    asm("v_min3_f32 %0, %1, %2, %3" : "=v"(d) : "v"(a), "v"(b), "v"(c));
    return d;
}

// Stage 1: grid = PB * VCH blocks. Block (pb, c): points [pb*2048, +2048),
// verts [c*313, min(+313, NV)). 8 pts/thread; verts staged once in LDS.
__global__ void __launch_bounds__(256, 4)
stage1(const float* __restrict__ verts, const float4* __restrict__ bds4,
       const int* __restrict__ idx, float* __restrict__ pmin) {
    __shared__ float4 sv[SVMAX];
    const int tid = threadIdx.x;
    const int pb  = blockIdx.x & (PB - 1);
    const int c   = blockIdx.x >> 4;
    const int b   = pb >> 1;            // 2 point-blocks per batch
    const int p0  = pb * PTSB;
    const int v0  = c * CH;
    const int vend = (v0 + CH < NV) ? (v0 + CH) : NV;
    const int tn  = vend - v0;
    const int tn4 = (tn + 3) & ~3;

    // stage verts as (-2x, -2y, -2z, |v|^2); sentinel-pad to multiple of 4
    for (int i = tid; i < tn4; i += 256) {
        float4 q;
        if (i < tn) {
            const float* vp = verts + (size_t)(b * NV + v0 + i) * 3;
            float x = vp[0], y = vp[1], z = vp[2];
            q = make_float4(-2.0f * x, -2.0f * y, -2.0f * z, x * x + y * y + z * z);
        } else {
            q = make_float4(0.0f, 0.0f, 0.0f, 3.4e38f);  // never wins the min
        }
        sv[i] = q;
    }

    float bx[8], by[8], bz[8], m[8];
#pragma unroll
    for (int k = 0; k < 8; ++k) {
        int pt = p0 + tid + k * 256;
        float4 bp = bds4[(size_t)b * NB + idx[pt & (NS - 1)]];
        bx[k] = bp.x; by[k] = bp.y; bz[k] = bp.z;
        m[k] = FLT_MAX;
    }
    __syncthreads();

    for (int v = 0; v < tn4; v += 4) {
        float4 q0 = sv[v], q1 = sv[v + 1], q2 = sv[v + 2], q3 = sv[v + 3];
#pragma unroll
        for (int k = 0; k < 8; ++k) {
            float t0 = fmaf(bx[k], q0.x, fmaf(by[k], q0.y, fmaf(bz[k], q0.z, q0.w)));
            float t1 = fmaf(bx[k], q1.x, fmaf(by[k], q1.y, fmaf(bz[k], q1.z, q1.w)));
            float t2 = fmaf(bx[k], q2.x, fmaf(by[k], q2.y, fmaf(bz[k], q2.z, q2.w)));
            float t3 = fmaf(bx[k], q3.x, fmaf(by[k], q3.y, fmaf(bz[k], q3.z, q3.w)));
            m[k] = min3f(m[k], t0, t1);
            m[k] = min3f(m[k], t2, t3);
        }
    }

#pragma unroll
    for (int k = 0; k < 8; ++k)
        pmin[(size_t)c * NPTS + p0 + tid + k * 256] = m[k];
}

// Stage 2: combine chunk mins, add sq_b, apply mask, per-block sum.
__global__ void stage2(const float* __restrict__ pmin, const float4* __restrict__ bds4,
                       const int* __restrict__ idx, float* __restrict__ bsum) {
    int pt = blockIdx.x * 256 + threadIdx.x;
    int b = pt >> 12, s = pt & (NS - 1);
    float4 bp = bds4[(size_t)b * NB + idx[s]];
    float md = FLT_MAX;
#pragma unroll 8
    for (int c = 0; c < VCH; ++c)
        md = fminf(md, pmin[(size_t)c * NPTS + pt]);
    float sqb = bp.x * bp.x + bp.y * bp.y + bp.z * bp.z;
    float val = (md + sqb) * bp.w * (1.0f / (float)NPTS);
    for (int o = 32; o > 0; o >>= 1) val += __shfl_down(val, o, 64);
    __shared__ float red[4];
    if ((threadIdx.x & 63) == 0) red[threadIdx.x >> 6] = val;
    __syncthreads();
    if (threadIdx.x == 0) bsum[blockIdx.x] = red[0] + red[1] + red[2] + red[3];
}

// Stage 3: final sum of 128 block partials -> scalar
__global__ void stage3(const float* __restrict__ bsum, float* __restrict__ out) {
    float v = bsum[threadIdx.x];  // 128 threads
    for (int o = 32; o > 0; o >>= 1) v += __shfl_down(v, o, 64);
    __shared__ float r[2];
    if ((threadIdx.x & 63) == 0) r[threadIdx.x >> 6] = v;
    __syncthreads();
    if (threadIdx.x == 0) out[0] = r[0] + r[1];
}

extern "C" void kernel_launch(void* const* d_in, const int* in_sizes, int n_in,
                              void* d_out, int out_size, void* d_ws, size_t ws_size,
                              hipStream_t stream) {
    const float*  verts = (const float*)d_in[0];
    const float4* bds4  = (const float4*)d_in[1];  // (BT, NB, 4) rows
    const int*    idx   = (const int*)d_in[3];     // int32
    float* out = (float*)d_out;

    char* ws = (char*)d_ws;
    float* pmin = (float*)ws;                                   // 32*32768*4 = 4 MB
    float* bsum = (float*)(ws + (size_t)VCH * NPTS * sizeof(float));  // 128 floats

    stage1<<<PB * VCH, 256, 0, stream>>>(verts, bds4, idx, pmin);
    stage2<<<NPTS / 256, 256, 0, stream>>>(pmin, bds4, idx, bsum);
    stage3<<<1, 128, 0, stream>>>(bsum, out);
}